// Round 12
// baseline (14.713 us; speedup 1.0000x reference)
//
#include <hip/hip_runtime.h>
#include <math.h>

// MorphLayer via max-product identity (exp monotone, exp∘log∘clamp = clamp):
//   exp(max_k(log(max(±x,eps)) + w_k)) = max_k( max(±x,eps) * exp(w_k) )
// Negation identity: max(-v,e)*w = max(-(v*w), e*w); eps-term ~1e-12 -> init 0.
// R12: R9 structure (4 outputs/thread, 8 waves/SIMD, 2048 blocks — the config
// measured at VALUBusy=80%) + max3 tap-pairing across CHUNK PAIRS:
// two (c,di) rows live at once, taps paired -> v_max3_f32 everywhere.
// 340 issues/thread vs R9's 540 at IDENTICAL occupancy/LDS/store structure.

#define BB 16
#define CC 3
#define HH 66
#define WW 66
#define HO 64
#define WO 64
#define FF 32
#define KK 27
#define FPB 4               // filters per block (1 per wave)
#define FG (FF / FPB)       // 8 filter groups
#define ROWS 4              // output rows per block
#define IR (ROWS + 2)       // staged input rows = 6
#define LP 68               // padded LDS row length (16B-aligned b128)
#define WSTRIDE 56          // per-wave weight block stride (floats)

typedef float f32x2 __attribute__((ext_vector_type(2)));
typedef float f32x4 __attribute__((ext_vector_type(4)));

__global__ __launch_bounds__(256, 8)
void morph_tile(const float* __restrict__ x,
                const float* __restrict__ k1,
                const float* __restrict__ k2,
                const float* __restrict__ bias,
                float* __restrict__ out) {
    __shared__ __align__(16) float xs[CC * IR * LP];    // 4896 B
    __shared__ __align__(16) float wl[FPB * WSTRIDE];   // 896 B

    const int tid = threadIdx.x;
    int bid = blockIdx.x;
    const int fg = bid & (FG - 1); bid >>= 3;   // filter group 0..7
    const int rb = bid & 15;       bid >>= 4;   // row band 0..15
    const int b  = bid;                         // batch
    const int f0 = fg * FPB;
    const int ho0 = rb * ROWS;

    // ---- per-wave weights: wl[w*WSTRIDE + k*2 + h] = exp((h?k2:k1)[k][f0+w]) ----
    if (tid < FPB * KK * 2) {
        const int w_  = tid / (KK * 2);
        const int rem = tid - w_ * (KK * 2);
        const int k   = rem >> 1;
        const int h   = rem & 1;
        const float wv = h ? k2[k * FF + f0 + w_] : k1[k * FF + f0 + w_];
        wl[w_ * WSTRIDE + k * 2 + h] = expf(wv);
    }
    // ---- stage x window (rows ho0..ho0+5, 3 channels), padded rows ----
    const float* xbase = x + (size_t)b * CC * HH * WW;
    for (int i = tid; i < CC * IR * WW; i += 256) {
        const int c   = i / (IR * WW);
        const int rem = i - c * (IR * WW);
        const int row = rem / WW;
        const int col = rem - row * WW;
        xs[(c * IR + row) * LP + col] = xbase[(c * HH + ho0 + row) * WW + col];
    }
    __syncthreads();

    const int w   = tid >> 6;          // wave = filter index within group
    const int l   = tid & 63;
    const int rr  = l >> 4;            // row within band, 0..3
    const int wo4 = (l & 15) * 4;      // first output col

    const float* wlw = wl + w * WSTRIDE;
    const int f = f0 + w;

    // 16 accumulator chains: 4 cols x {m11,m12,m21,m22}
    float m11_0 = 0.f, m11_1 = 0.f, m11_2 = 0.f, m11_3 = 0.f;
    float m12_0 = 0.f, m12_1 = 0.f, m12_2 = 0.f, m12_3 = 0.f;
    float m21_0 = 0.f, m21_1 = 0.f, m21_2 = 0.f, m21_3 = 0.f;
    float m22_0 = 0.f, m22_1 = 0.f, m22_2 = 0.f, m22_3 = 0.f;

    // load one chunk row (ci = c*3+di): 6 cols wo4..wo4+5 into S[0..5]
#define LOADC(S, ci) { \
        const int base_ = ((((ci) / 3) * IR + rr + ((ci) % 3)) * LP + wo4); \
        const f32x4 xq_ = *(const f32x4*)(xs + base_); \
        const f32x2 xr_ = *(const f32x2*)(xs + base_ + 4); \
        S##0 = xq_.x; S##1 = xq_.y; S##2 = xq_.z; S##3 = xq_.w; \
        S##4 = xr_.x; S##5 = xr_.y; \
    }

#define SEL(S, j) S##j

    // paired taps: tap(SA,djA,kA) with tap(SB,djB,kB): 8 pk_mul + 16 max3
#define TAPPAIR(SA, djA, kA, SB, djB, kB) { \
        const f32x2 eA_ = *(const f32x2*)(wlw + (kA) * 2); \
        const f32x2 eB_ = *(const f32x2*)(wlw + (kB) * 2); \
        const f32x2 e1A = {eA_.x, eA_.x}, e2A = {eA_.y, eA_.y}; \
        const f32x2 e1B = {eB_.x, eB_.x}, e2B = {eB_.y, eB_.y}; \
        const f32x2 abA = {PASTE(SA, djA), PASTE(SA, PLUS1(djA))}; \
        const f32x2 cdA = {PASTE(SA, PLUS2(djA)), PASTE(SA, PLUS3(djA))}; \
        const f32x2 abB = {PASTE(SB, djB), PASTE(SB, PLUS1(djB))}; \
        const f32x2 cdB = {PASTE(SB, PLUS2(djB)), PASTE(SB, PLUS3(djB))}; \
        const f32x2 pA1 = abA * e1A, qA1 = cdA * e1A; \
        const f32x2 pA2 = abA * e2A, qA2 = cdA * e2A; \
        const f32x2 pB1 = abB * e1B, qB1 = cdB * e1B; \
        const f32x2 pB2 = abB * e2B, qB2 = cdB * e2B; \
        m11_0 = fmaxf(fmaxf(m11_0,  pA1.x),  pB1.x); \
        m11_1 = fmaxf(fmaxf(m11_1,  pA1.y),  pB1.y); \
        m11_2 = fmaxf(fmaxf(m11_2,  qA1.x),  qB1.x); \
        m11_3 = fmaxf(fmaxf(m11_3,  qA1.y),  qB1.y); \
        m12_0 = fmaxf(fmaxf(m12_0,  pA2.x),  pB2.x); \
        m12_1 = fmaxf(fmaxf(m12_1,  pA2.y),  pB2.y); \
        m12_2 = fmaxf(fmaxf(m12_2,  qA2.x),  qB2.x); \
        m12_3 = fmaxf(fmaxf(m12_3,  qA2.y),  qB2.y); \
        m21_0 = fmaxf(fmaxf(m21_0, -pA1.x), -pB1.x); \
        m21_1 = fmaxf(fmaxf(m21_1, -pA1.y), -pB1.y); \
        m21_2 = fmaxf(fmaxf(m21_2, -qA1.x), -qB1.x); \
        m21_3 = fmaxf(fmaxf(m21_3, -qA1.y), -qB1.y); \
        m22_0 = fmaxf(fmaxf(m22_0, -pA2.x), -pB2.x); \
        m22_1 = fmaxf(fmaxf(m22_1, -pA2.y), -pB2.y); \
        m22_2 = fmaxf(fmaxf(m22_2, -qA2.x), -qB2.x); \
        m22_3 = fmaxf(fmaxf(m22_3, -qA2.y), -qB2.y); \
    }

#define PASTE_(a, b) a##b
#define PASTE(a, b) PASTE_(a, b)
#define PLUS1(x) PASTE_(P1_, x)
#define PLUS2(x) PASTE_(P2_, x)
#define PLUS3(x) PASTE_(P3_, x)
#define P1_0 1
#define P1_1 2
#define P1_2 3
#define P2_0 2
#define P2_1 3
#define P2_2 4
#define P3_0 3
#define P3_1 4
#define P3_2 5

    // single tap: 4 pk_mul + 16 v_max
#define TAPONE(SA, djA, kA) { \
        const f32x2 eA_ = *(const f32x2*)(wlw + (kA) * 2); \
        const f32x2 e1A = {eA_.x, eA_.x}, e2A = {eA_.y, eA_.y}; \
        const f32x2 abA = {PASTE(SA, djA), PASTE(SA, PLUS1(djA))}; \
        const f32x2 cdA = {PASTE(SA, PLUS2(djA)), PASTE(SA, PLUS3(djA))}; \
        const f32x2 p1 = abA * e1A, q1 = cdA * e1A; \
        const f32x2 p2 = abA * e2A, q2 = cdA * e2A; \
        m11_0 = fmaxf(m11_0,  p1.x); m11_1 = fmaxf(m11_1,  p1.y); \
        m11_2 = fmaxf(m11_2,  q1.x); m11_3 = fmaxf(m11_3,  q1.y); \
        m12_0 = fmaxf(m12_0,  p2.x); m12_1 = fmaxf(m12_1,  p2.y); \
        m12_2 = fmaxf(m12_2,  q2.x); m12_3 = fmaxf(m12_3,  q2.y); \
        m21_0 = fmaxf(m21_0, -p1.x); m21_1 = fmaxf(m21_1, -p1.y); \
        m21_2 = fmaxf(m21_2, -q1.x); m21_3 = fmaxf(m21_3, -q1.y); \
        m22_0 = fmaxf(m22_0, -p2.x); m22_1 = fmaxf(m22_1, -p2.y); \
        m22_2 = fmaxf(m22_2, -q2.x); m22_3 = fmaxf(m22_3, -q2.y); \
    }

    // chunk-pair (ciA, ciB): 12 window floats live; taps paired across chunks
#define CHUNKPAIR(ciA, ciB) { \
        float a0, a1, a2, a3, a4, a5; \
        float c0, c1, c2, c3, c4, c5; \
        LOADC(a, ciA) \
        LOADC(c, ciB) \
        TAPPAIR(a, 0, (ciA)*3 + 0, c, 0, (ciB)*3 + 0) \
        TAPPAIR(a, 1, (ciA)*3 + 1, c, 1, (ciB)*3 + 1) \
        TAPPAIR(a, 2, (ciA)*3 + 2, c, 2, (ciB)*3 + 2) \
    }

    CHUNKPAIR(0, 1)
    CHUNKPAIR(2, 3)
    CHUNKPAIR(4, 5)
    CHUNKPAIR(6, 7)
    {   // tail chunk ci=8: taps k=24,25 paired within chunk + single k=26
        float a0, a1, a2, a3, a4, a5;
        LOADC(a, 8)
        TAPPAIR(a, 0, 24, a, 1, 25)
        TAPONE(a, 2, 26)
    }

#undef CHUNKPAIR
#undef TAPONE
#undef TAPPAIR
#undef LOADC

    const float bs = bias[f];
    f32x4 res;
    res.x = m11_0 - m12_0 - m21_0 + m22_0 + bs;
    res.y = m11_1 - m12_1 - m21_1 + m22_1 + bs;
    res.z = m11_2 - m12_2 - m21_2 + m22_2 + bs;
    res.w = m11_3 - m12_3 - m21_3 + m22_3 + bs;

    *(f32x4*)(out + (((size_t)b * FF + f) * HO + ho0 + rr) * WO + wo4) = res;
}

extern "C" void kernel_launch(void* const* d_in, const int* in_sizes, int n_in,
                              void* d_out, int out_size, void* d_ws, size_t ws_size,
                              hipStream_t stream) {
    const float* x    = (const float*)d_in[0];
    const float* k1   = (const float*)d_in[1];
    const float* k2   = (const float*)d_in[2];
    const float* bias = (const float*)d_in[3];
    float* out = (float*)d_out;

    const int nblocks = BB * (HO / ROWS) * FG;  // 2048
    morph_tile<<<dim3(nblocks), dim3(256), 0, stream>>>(x, k1, k2, bias, out);
}